// Round 2
// baseline (21785.892 us; speedup 1.0000x reference)
//
#include <hip/hip_runtime.h>
#include <hip/hip_bf16.h>
#include <stdint.h>

// RNN_75531294867647 on MI355X (gfx950)
// B=128 S=512 I=256 H=1024 O=256, fp32 in/out, LeakyReLU slope 0.01.
//
//   split:  x -> bf16 hi; Wi -> hi/lo; Wh -> WA hi (cols 0:1024), WB hi (cols 1024:2048)
//   gemm1:  xproj = LReLU(x @ Wi^T + bi) -> bf16 hi, layout [S][B][H]  (128MB)
//   recur:  h <- LReLU(xproj_t @ WA^T + bh + (h_hi + h_lo) @ WB^T), 512 steps.
//           128 persistent wgs (grid 256, half exit): 4 batch-groups x 32 j-wgs;
//           per-wg LDS: WA+WB 32-row slices (128KB, XOR-swizzled); h state hi/lo
//           bf16 in global; per-group 32-arrival device-scope atomic barrier.
//   out:    out = h @ Wo^T + bo (f32 VALU, tiny)
//
// Workspace ~174MB with a ws_size guard (falls back to zero-output = diagnostic).

#define LRELU_SLOPE 0.01f

typedef unsigned short u16;
typedef __bf16 bf16x8 __attribute__((ext_vector_type(8)));
typedef short  s16x8  __attribute__((ext_vector_type(8)));
typedef float  f32x4  __attribute__((ext_vector_type(4)));
typedef u16    u16x4  __attribute__((ext_vector_type(4)));

__device__ __forceinline__ u16 f2bf(float f) {
  uint32_t u = __builtin_bit_cast(uint32_t, f);
  return (u16)((u + 0x7FFFu + ((u >> 16) & 1u)) >> 16);   // RNE
}
__device__ __forceinline__ float bf2f(u16 h) {
  uint32_t u = ((uint32_t)h) << 16;
  return __builtin_bit_cast(float, u);
}
__device__ __forceinline__ f32x4 mfma16(s16x8 a, s16x8 b, f32x4 c) {
  return __builtin_amdgcn_mfma_f32_16x16x32_bf16(
      __builtin_bit_cast(bf16x8, a), __builtin_bit_cast(bf16x8, b), c, 0, 0, 0);
}
__device__ __forceinline__ void gload_lds16(const void* g, void* l) {
  __builtin_amdgcn_global_load_lds(
      (const __attribute__((address_space(1))) void*)g,
      (__attribute__((address_space(3))) void*)l, 16, 0, 0);
}

// ---------------- fallback / split kernels -----------------------------------

__global__ void zero_out_k(float* __restrict__ out, int n) {
  int i = blockIdx.x * 256 + threadIdx.x;
  if (i < n) out[i] = 0.f;
}

__global__ void splitHi(const float* __restrict__ src, u16* __restrict__ hi, long n4) {
  long i = (long)blockIdx.x * 256 + threadIdx.x;
  if (i >= n4) return;
  float4 v = ((const float4*)src)[i];
  float a[4] = {v.x, v.y, v.z, v.w};
  u16x4 hv;
#pragma unroll
  for (int j = 0; j < 4; ++j) hv[j] = f2bf(a[j]);
  ((u16x4*)hi)[i] = hv;
}

__global__ void splitHiLo(const float* __restrict__ src, u16* __restrict__ hi,
                          u16* __restrict__ lo, long n4) {
  long i = (long)blockIdx.x * 256 + threadIdx.x;
  if (i >= n4) return;
  float4 v = ((const float4*)src)[i];
  float a[4] = {v.x, v.y, v.z, v.w};
  u16x4 hv, lv;
#pragma unroll
  for (int j = 0; j < 4; ++j) {
    u16 h = f2bf(a[j]);
    hv[j] = h;
    lv[j] = f2bf(a[j] - bf2f(h));
  }
  ((u16x4*)hi)[i] = hv;
  ((u16x4*)lo)[i] = lv;
}

// Wh [1024][2048] -> WAh = hi(cols 0:1024), WBh = hi(cols 1024:2048)
__global__ void split_wh(const float* __restrict__ Wh,
                         u16* __restrict__ WAh, u16* __restrict__ WBh) {
  long i4 = ((long)blockIdx.x * 256 + threadIdx.x) * 4;   // 1024*2048 elems
  int j = (int)(i4 >> 11), k2 = (int)(i4 & 2047);
  float4 v = *(const float4*)&Wh[i4];
  float a[4] = {v.x, v.y, v.z, v.w};
  u16x4 hv;
#pragma unroll
  for (int q = 0; q < 4; ++q) hv[q] = f2bf(a[q]);
  if (k2 < 1024) *(u16x4*)&WAh[(long)j * 1024 + k2]          = hv;
  else           *(u16x4*)&WBh[(long)j * 1024 + (k2 - 1024)] = hv;
}

// ---------------- gemm1: xproj = LReLU(x@Wi^T + bi) --------------------------
// A = xh [65536,256]; B0/B1 = Wi hi/lo [1024,256]; acc += A*B0 + A*B1 (f32 sum).
// Out layout [s][b][col] bf16 hi, m = b*512 + s.

__global__ __launch_bounds__(256, 2)
void gemm_xproj(const u16* __restrict__ A, const u16* __restrict__ B0,
                const u16* __restrict__ B1, const float* __restrict__ bias,
                u16* __restrict__ outP) {
  __shared__ u16 sA[128 * 64], sB0[128 * 64], sB1[128 * 64];
  const int tid = threadIdx.x, wid = tid >> 6, lane = tid & 63;
  const int lrow = lane & 15, lgrp = lane >> 4;
  const int wm = wid >> 1, wn = wid & 1;
  const size_t m0 = (size_t)blockIdx.x * 128;
  const int n0 = blockIdx.y * 128;
  const int srow = tid >> 3, scol = (tid & 7) << 3;
  f32x4 acc[4][4] = {};

  for (int kt = 0; kt < 4; ++kt) {
    const int kph = kt << 6;
    __syncthreads();
#pragma unroll
    for (int sh = 0; sh < 4; ++sh) {
      const int r = sh * 32 + srow;
      gload_lds16(A  + (m0 + r) * 256 + kph + scol,          &sA [sh * 2048 + wid * 512]);
      gload_lds16(B0 + (size_t)(n0 + r) * 256 + kph + scol,  &sB0[sh * 2048 + wid * 512]);
      gload_lds16(B1 + (size_t)(n0 + r) * 256 + kph + scol,  &sB1[sh * 2048 + wid * 512]);
    }
    __syncthreads();
#pragma unroll
    for (int kk = 0; kk < 2; ++kk) {
      s16x8 bf0[4], bf1[4];
#pragma unroll
      for (int ni = 0; ni < 4; ++ni) {
        bf0[ni] = *(const s16x8*)&sB0[(wn * 64 + ni * 16 + lrow) * 64 + kk * 32 + lgrp * 8];
        bf1[ni] = *(const s16x8*)&sB1[(wn * 64 + ni * 16 + lrow) * 64 + kk * 32 + lgrp * 8];
      }
#pragma unroll
      for (int mi = 0; mi < 4; ++mi) {
        const s16x8 af = *(const s16x8*)&sA[(wm * 64 + mi * 16 + lrow) * 64 + kk * 32 + lgrp * 8];
#pragma unroll
        for (int ni = 0; ni < 4; ++ni) {
          acc[mi][ni] = mfma16(af, bf0[ni], acc[mi][ni]);
          acc[mi][ni] = mfma16(af, bf1[ni], acc[mi][ni]);
        }
      }
    }
  }
  // D layout: col=lane&15, row=4*(lane>>4)+reg
#pragma unroll
  for (int mi = 0; mi < 4; ++mi)
#pragma unroll
    for (int ni = 0; ni < 4; ++ni) {
      const int col = n0 + wn * 64 + ni * 16 + lrow;
      const float bv = bias[col];
#pragma unroll
      for (int r = 0; r < 4; ++r) {
        const size_t row = m0 + wm * 64 + mi * 16 + lgrp * 4 + r;
        float v = acc[mi][ni][r] + bv;
        v = (v >= 0.f) ? v : LRELU_SLOPE * v;
        const size_t b = row >> 9, s = row & 511;
        outP[(s * 128 + b) * 1024 + col] = f2bf(v);
      }
    }
}

// ---------------- recurrence (fused U) ---------------------------------------
// grid 256 (128 live), 256 thr. wg: g = wg&7 (<4), jw = wg>>3. b0=g*32, j0=jw*32.
// LDS: WA/WB rows [j0,j0+32) hi bf16, 16B-granule XOR swizzle slot = s^(r&7).
// 4 waves: wm=wid>>1 (b 16-row half), wn=wid&1 (j 16-col half); full k=1024 sweep,
// 3 chains: aU = xproj_t@WA^T, aW = h_hi@WB^T, aL = h_lo@WB^T (all f32 acc).
// Barrier: per-group 32-arrival device-scope atomic; one barrier/step suffices
// (reads of h_t finish before each wg's own arrive).

__global__ __launch_bounds__(256, 1)
void recur(const u16* __restrict__ WAh, const u16* __restrict__ WBh,
           const u16* __restrict__ xproj, const float* __restrict__ bh,
           u16* __restrict__ h0h, u16* __restrict__ h0l,
           u16* __restrict__ h1h, u16* __restrict__ h1l,
           unsigned* __restrict__ cnt) {
  const int wg = blockIdx.x;
  if ((wg & 7) >= 4) return;             // survivors: one XCD per group (heuristic)
  __shared__ u16 sWA[32 * 1024];
  __shared__ u16 sWB[32 * 1024];
  const int tid = threadIdx.x, wid = tid >> 6, lane = tid & 63;
  const int lrow = lane & 15, lgrp = lane >> 4;
  const int wm = wid >> 1, wn = wid & 1;
  const int g = wg & 7, jw = wg >> 3;
  const int b0 = g * 32, j0 = jw * 32;

  // one-time weight-slice load (LDS granule s of row r holds global granule s^(r&7))
  for (int i = tid; i < 32 * 128; i += 256) {
    const int r = i >> 7, s = i & 127, sg = s ^ (r & 7);
    *(s16x8*)&sWA[(size_t)i * 8] = *(const s16x8*)&WAh[(((size_t)(j0 + r)) << 10) + sg * 8];
    *(s16x8*)&sWB[(size_t)i * 8] = *(const s16x8*)&WBh[(((size_t)(j0 + r)) << 10) + sg * 8];
  }
  __syncthreads();

  const int wr = wn * 16 + lrow;          // weight row (output col within slice)
  const float bj = bh[j0 + wr];
  const int arow = b0 + wm * 16 + lrow;   // A-operand row (batch index)
  unsigned* myc = &cnt[g * 64];

  for (int t = 0; t < 512; ++t) {
    const u16* hh = (t & 1) ? h1h : h0h;
    const u16* hl = (t & 1) ? h1l : h0l;
    u16* ohh = (t & 1) ? h0h : h1h;
    u16* ohl = (t & 1) ? h0l : h1l;
    const u16* xp  = xproj + ((size_t)t * 128 + arow) * 1024;
    const u16* hhp = hh + ((size_t)arow << 10);
    const u16* hlp = hl + ((size_t)arow << 10);

    f32x4 aW = {0.f, 0.f, 0.f, 0.f}, aL = {0.f, 0.f, 0.f, 0.f}, aU = {0.f, 0.f, 0.f, 0.f};
#pragma unroll
    for (int kc = 0; kc < 32; ++kc) {
      const int k0 = kc * 32 + lgrp * 8;
      const int slot = (((kc * 4 + lgrp) ^ (wr & 7)) << 3);
      const s16x8 xv = *(const s16x8*)&xp[k0];
      const s16x8 wa = *(const s16x8*)&sWA[((size_t)wr << 10) + slot];
      aU = mfma16(xv, wa, aU);
      const s16x8 ah = *(const s16x8*)&hhp[k0];
      const s16x8 al = *(const s16x8*)&hlp[k0];
      const s16x8 wb = *(const s16x8*)&sWB[((size_t)wr << 10) + slot];
      aW = mfma16(ah, wb, aW);
      aL = mfma16(al, wb, aL);
    }
    // D: col = lane&15 -> j0 + wr; row = 4*lgrp + r -> b0 + wm*16 + lgrp*4 + r
#pragma unroll
    for (int r = 0; r < 4; ++r) {
      float v = aW[r] + aL[r] + aU[r] + bj;
      v = (v >= 0.f) ? v : LRELU_SLOPE * v;
      const u16 hB = f2bf(v);
      const size_t oi = (((size_t)(b0 + wm * 16 + lgrp * 4 + r)) << 10) + j0 + wr;
      ohh[oi] = hB;
      ohl[oi] = f2bf(v - bf2f(hB));
    }
    __threadfence();                      // per-wave: waitcnt + L2 writeback (release)
    __syncthreads();
    if (tid == 0) {
      __hip_atomic_fetch_add(myc, 1u, __ATOMIC_RELEASE, __HIP_MEMORY_SCOPE_AGENT);
      const unsigned target = (unsigned)(t + 1) * 32u;
      while (__hip_atomic_load(myc, __ATOMIC_ACQUIRE, __HIP_MEMORY_SCOPE_AGENT) < target)
        __builtin_amdgcn_s_sleep(1);
    }
    __syncthreads();
  }
}

// ---------------- output GEMM (tiny, f32 VALU) -------------------------------

__global__ __launch_bounds__(256)
void out_gemm(const u16* __restrict__ hh, const u16* __restrict__ hl,
              const float* __restrict__ Wo, const float* __restrict__ bo,
              float* __restrict__ out) {
  __shared__ float hrow[1024];
  const int b = blockIdx.x, tid = threadIdx.x;
  for (int k = tid; k < 1024; k += 256)
    hrow[k] = bf2f(hh[((size_t)b << 10) + k]) + bf2f(hl[((size_t)b << 10) + k]);
  __syncthreads();
  const float* wo = Wo + (size_t)tid * 1024;
  float s0 = 0.f, s1 = 0.f, s2 = 0.f, s3 = 0.f;
  for (int k = 0; k < 1024; k += 4) {
    s0 = fmaf(wo[k + 0], hrow[k + 0], s0);
    s1 = fmaf(wo[k + 1], hrow[k + 1], s1);
    s2 = fmaf(wo[k + 2], hrow[k + 2], s2);
    s3 = fmaf(wo[k + 3], hrow[k + 3], s3);
  }
  out[(size_t)b * 256 + tid] = s0 + s1 + s2 + s3 + bo[tid];
}

// ---------------- launch ------------------------------------------------------

extern "C" void kernel_launch(void* const* d_in, const int* in_sizes, int n_in,
                              void* d_out, int out_size, void* d_ws, size_t ws_size,
                              hipStream_t stream) {
  const float* x  = (const float*)d_in[0];
  const float* Wi = (const float*)d_in[1];
  const float* bi = (const float*)d_in[2];
  const float* Wh = (const float*)d_in[3];
  const float* bh = (const float*)d_in[4];
  const float* Wo = (const float*)d_in[5];
  const float* bo = (const float*)d_in[6];

  char* w = (char*)d_ws;
  size_t off = 0;
  auto alloc = [&](size_t bytes) -> void* {
    void* p = w + off;
    off = (off + bytes + 255) & ~(size_t)255;
    return p;
  };
  u16* xh  = (u16*)alloc(33554432ull);    // x hi          [65536,256]
  u16* ph  = (u16*)alloc(134217728ull);   // xproj hi      [512][128][1024]
  u16* Wih = (u16*)alloc(524288ull);
  u16* Wil = (u16*)alloc(524288ull);
  u16* WAh = (u16*)alloc(2097152ull);     // Wh[:, :1024] hi
  u16* WBh = (u16*)alloc(2097152ull);     // Wh[:, 1024:] hi
  u16* h0h = (u16*)alloc(262144ull);
  u16* h0l = (u16*)alloc(262144ull);
  u16* h1h = (u16*)alloc(262144ull);
  u16* h1l = (u16*)alloc(262144ull);
  unsigned* cnt = (unsigned*)alloc(4096ull);
  const size_t needed = off;              // ~174 MB

  if (ws_size < needed) {                 // diagnostic fallback: absmax == max|ref|
    zero_out_k<<<(out_size + 255) / 256, 256, 0, stream>>>((float*)d_out, out_size);
    return;
  }

  hipMemsetAsync(cnt, 0, 4096, stream);
  hipMemsetAsync(h0h, 0, 262144, stream); // h_0 = 0
  hipMemsetAsync(h0l, 0, 262144, stream);

  splitHi  <<<16384, 256, 0, stream>>>(x, xh, 4194304);
  splitHiLo<<<256,   256, 0, stream>>>(Wi, Wih, Wil, 65536);
  split_wh <<<2048,  256, 0, stream>>>(Wh, WAh, WBh);

  gemm_xproj<<<dim3(512, 8), 256, 0, stream>>>(xh, Wih, Wil, bi, ph);

  recur<<<256, 256, 0, stream>>>(WAh, WBh, ph, bh, h0h, h0l, h1h, h1l, cnt);
  out_gemm<<<128, 256, 0, stream>>>(h0h, h0l, Wo, bo, (float*)d_out);
}

// Round 3
// 6276.805 us; speedup vs baseline: 3.4709x; 3.4709x over previous
//
#include <hip/hip_runtime.h>
#include <hip/hip_bf16.h>
#include <stdint.h>

// RNN_75531294867647 on MI355X (gfx950)
// B=128 S=512 I=256 H=1024 O=256, fp32 in/out, LeakyReLU slope 0.01.
//
//   split:  x -> bf16 hi; Wi -> hi/lo; Wh -> WA hi (cols 0:1024), WB hi (cols 1024:2048)
//   gemm1:  xproj = LReLU(x @ Wi^T + bi) -> bf16 hi, layout [S][B][H]  (128MB)
//   recur:  h <- LReLU(xproj_t @ WA^T + bh + (h_hi + h_lo) @ WB^T), 512 steps.
//           128 persistent wgs: 4 batch-groups x 32 j-wgs. Exchange of h via
//           Infinity-Cache-direct (sc0 sc1) loads/stores -> NO wbl2/inv fences.
//           Per-group 32-arrival relaxed agent atomic barrier, all-lane spin.
//   out:    out = h @ Wo^T + bo (f32 VALU, tiny)

#define LRELU_SLOPE 0.01f

typedef unsigned short u16;
typedef __bf16 bf16x8 __attribute__((ext_vector_type(8)));
typedef short  s16x8  __attribute__((ext_vector_type(8)));
typedef float  f32x4  __attribute__((ext_vector_type(4)));
typedef u16    u16x4  __attribute__((ext_vector_type(4)));

__device__ __forceinline__ u16 f2bf(float f) {
  uint32_t u = __builtin_bit_cast(uint32_t, f);
  return (u16)((u + 0x7FFFu + ((u >> 16) & 1u)) >> 16);   // RNE
}
__device__ __forceinline__ float bf2f(u16 h) {
  uint32_t u = ((uint32_t)h) << 16;
  return __builtin_bit_cast(float, u);
}
__device__ __forceinline__ f32x4 mfma16(s16x8 a, s16x8 b, f32x4 c) {
  return __builtin_amdgcn_mfma_f32_16x16x32_bf16(
      __builtin_bit_cast(bf16x8, a), __builtin_bit_cast(bf16x8, b), c, 0, 0, 0);
}
__device__ __forceinline__ void gload_lds16(const void* g, void* l) {
  __builtin_amdgcn_global_load_lds(
      (const __attribute__((address_space(1))) void*)g,
      (__attribute__((address_space(3))) void*)l, 16, 0, 0);
}

// ---------------- fallback / split kernels -----------------------------------

__global__ void zero_out_k(float* __restrict__ out, int n) {
  int i = blockIdx.x * 256 + threadIdx.x;
  if (i < n) out[i] = 0.f;
}

__global__ void splitHi(const float* __restrict__ src, u16* __restrict__ hi, long n4) {
  long i = (long)blockIdx.x * 256 + threadIdx.x;
  if (i >= n4) return;
  float4 v = ((const float4*)src)[i];
  float a[4] = {v.x, v.y, v.z, v.w};
  u16x4 hv;
#pragma unroll
  for (int j = 0; j < 4; ++j) hv[j] = f2bf(a[j]);
  ((u16x4*)hi)[i] = hv;
}

__global__ void splitHiLo(const float* __restrict__ src, u16* __restrict__ hi,
                          u16* __restrict__ lo, long n4) {
  long i = (long)blockIdx.x * 256 + threadIdx.x;
  if (i >= n4) return;
  float4 v = ((const float4*)src)[i];
  float a[4] = {v.x, v.y, v.z, v.w};
  u16x4 hv, lv;
#pragma unroll
  for (int j = 0; j < 4; ++j) {
    u16 h = f2bf(a[j]);
    hv[j] = h;
    lv[j] = f2bf(a[j] - bf2f(h));
  }
  ((u16x4*)hi)[i] = hv;
  ((u16x4*)lo)[i] = lv;
}

// Wh [1024][2048] -> WAh = hi(cols 0:1024), WBh = hi(cols 1024:2048)
__global__ void split_wh(const float* __restrict__ Wh,
                         u16* __restrict__ WAh, u16* __restrict__ WBh) {
  long i4 = ((long)blockIdx.x * 256 + threadIdx.x) * 4;   // 1024*2048 elems
  int j = (int)(i4 >> 11), k2 = (int)(i4 & 2047);
  float4 v = *(const float4*)&Wh[i4];
  float a[4] = {v.x, v.y, v.z, v.w};
  u16x4 hv;
#pragma unroll
  for (int q = 0; q < 4; ++q) hv[q] = f2bf(a[q]);
  if (k2 < 1024) *(u16x4*)&WAh[(long)j * 1024 + k2]          = hv;
  else           *(u16x4*)&WBh[(long)j * 1024 + (k2 - 1024)] = hv;
}

// ---------------- gemm1: xproj = LReLU(x@Wi^T + bi) --------------------------

__global__ __launch_bounds__(256, 2)
void gemm_xproj(const u16* __restrict__ A, const u16* __restrict__ B0,
                const u16* __restrict__ B1, const float* __restrict__ bias,
                u16* __restrict__ outP) {
  __shared__ u16 sA[128 * 64], sB0[128 * 64], sB1[128 * 64];
  const int tid = threadIdx.x, wid = tid >> 6, lane = tid & 63;
  const int lrow = lane & 15, lgrp = lane >> 4;
  const int wm = wid >> 1, wn = wid & 1;
  const size_t m0 = (size_t)blockIdx.x * 128;
  const int n0 = blockIdx.y * 128;
  const int srow = tid >> 3, scol = (tid & 7) << 3;
  f32x4 acc[4][4] = {};

  for (int kt = 0; kt < 4; ++kt) {
    const int kph = kt << 6;
    __syncthreads();
#pragma unroll
    for (int sh = 0; sh < 4; ++sh) {
      const int r = sh * 32 + srow;
      gload_lds16(A  + (m0 + r) * 256 + kph + scol,          &sA [sh * 2048 + wid * 512]);
      gload_lds16(B0 + (size_t)(n0 + r) * 256 + kph + scol,  &sB0[sh * 2048 + wid * 512]);
      gload_lds16(B1 + (size_t)(n0 + r) * 256 + kph + scol,  &sB1[sh * 2048 + wid * 512]);
    }
    __syncthreads();
#pragma unroll
    for (int kk = 0; kk < 2; ++kk) {
      s16x8 bf0[4], bf1[4];
#pragma unroll
      for (int ni = 0; ni < 4; ++ni) {
        bf0[ni] = *(const s16x8*)&sB0[(wn * 64 + ni * 16 + lrow) * 64 + kk * 32 + lgrp * 8];
        bf1[ni] = *(const s16x8*)&sB1[(wn * 64 + ni * 16 + lrow) * 64 + kk * 32 + lgrp * 8];
      }
#pragma unroll
      for (int mi = 0; mi < 4; ++mi) {
        const s16x8 af = *(const s16x8*)&sA[(wm * 64 + mi * 16 + lrow) * 64 + kk * 32 + lgrp * 8];
#pragma unroll
        for (int ni = 0; ni < 4; ++ni) {
          acc[mi][ni] = mfma16(af, bf0[ni], acc[mi][ni]);
          acc[mi][ni] = mfma16(af, bf1[ni], acc[mi][ni]);
        }
      }
    }
  }
#pragma unroll
  for (int mi = 0; mi < 4; ++mi)
#pragma unroll
    for (int ni = 0; ni < 4; ++ni) {
      const int col = n0 + wn * 64 + ni * 16 + lrow;
      const float bv = bias[col];
#pragma unroll
      for (int r = 0; r < 4; ++r) {
        const size_t row = m0 + wm * 64 + mi * 16 + lgrp * 4 + r;
        float v = acc[mi][ni][r] + bv;
        v = (v >= 0.f) ? v : LRELU_SLOPE * v;
        const size_t b = row >> 9, s = row & 511;
        outP[(s * 128 + b) * 1024 + col] = f2bf(v);
      }
    }
}

// ---------------- recurrence (L3-direct exchange, no cache-maintenance) ------
// grid 128, 256 thr. wg: g = wg>>5 (batch rows b0=g*32..+32), jw = wg&31
// (cols j0=jw*32..+32). LDS: WA/WB 32-row slices, 16B-granule XOR swizzle.
// Per step: aU = xproj_t@WA^T (cacheable loads, overlaps barrier wait);
// spin cnt[g] >= 32*t (relaxed sc0sc1 poll); aW/aL = h_hi/h_lo @ WB^T with
// counted-vmcnt depth-2 chunk pipeline of sc0sc1 loads; LDS-bounce the 16x16
// f32 tile -> one dwordx4 sc0sc1 store per lane; __syncthreads (drains vmem);
// tid0 arrival add (relaxed agent).

#define ISSUE_CHUNK(J, SB)                                                        \
  {                                                                               \
    _Pragma("unroll") for (int q = 0; q < 4; ++q) {                               \
      const int k0_ = ((J) * 4 + q) * 32 + lgrp * 8;                              \
      asm volatile("global_load_dwordx4 %0, %1, off sc0 sc1"                      \
                   : "=v"(bufH[SB][q]) : "v"(hhp + k0_));                         \
      asm volatile("global_load_dwordx4 %0, %1, off sc0 sc1"                      \
                   : "=v"(bufL[SB][q]) : "v"(hlp + k0_));                         \
    }                                                                             \
  }

__global__ __launch_bounds__(256, 1)
void recur(const u16* __restrict__ WAh, const u16* __restrict__ WBh,
           const u16* __restrict__ xproj, const float* __restrict__ bh,
           u16* __restrict__ h0h, u16* __restrict__ h0l,
           u16* __restrict__ h1h, u16* __restrict__ h1l,
           unsigned* __restrict__ cnt) {
  __shared__ u16 sWA[32 * 1024];
  __shared__ u16 sWB[32 * 1024];
  __shared__ float sT[4][16][16];
  const int tid = threadIdx.x, wid = tid >> 6, lane = tid & 63;
  const int lrow = lane & 15, lgrp = lane >> 4;
  const int wm = wid >> 1, wn = wid & 1;
  const int wg = blockIdx.x, g = wg >> 5, jw = wg & 31;
  const int b0 = g * 32, j0 = jw * 32;

  for (int i = tid; i < 32 * 128; i += 256) {
    const int r = i >> 7, s = i & 127, sg = s ^ (r & 7);
    *(s16x8*)&sWA[(size_t)i * 8] = *(const s16x8*)&WAh[(((size_t)(j0 + r)) << 10) + sg * 8];
    *(s16x8*)&sWB[(size_t)i * 8] = *(const s16x8*)&WBh[(((size_t)(j0 + r)) << 10) + sg * 8];
  }
  __syncthreads();

  const int wr = wn * 16 + lrow;          // weight row = output col within slice
  const float bj = bh[j0 + wr];
  const int arow = b0 + wm * 16 + lrow;   // A-operand row (batch index)
  unsigned* myc = &cnt[g * 256];          // group counters 1KB apart
  const int sr = (lane & 31) >> 1, sh2 = lane & 1;  // store-lane mapping

  for (int t = 0; t < 512; ++t) {
    const u16* hh = (t & 1) ? h1h : h0h;
    const u16* hl = (t & 1) ? h1l : h0l;
    u16* ohh = (t & 1) ? h0h : h1h;
    u16* ohl = (t & 1) ? h0l : h1l;
    const u16* xp  = xproj + ((size_t)t * 128 + arow) * 1024;
    const u16* hhp = hh + ((size_t)arow << 10);
    const u16* hlp = hl + ((size_t)arow << 10);

    // ---- phase U: aU = xproj_t @ WA^T (independent of h_t) ----
    f32x4 aU = {0.f, 0.f, 0.f, 0.f};
#pragma unroll
    for (int kc = 0; kc < 32; ++kc) {
      const int k0 = kc * 32 + lgrp * 8;
      const int slot = (((kc * 4 + lgrp) ^ (wr & 7)) << 3);
      aU = mfma16(*(const s16x8*)&xp[k0],
                  *(const s16x8*)&sWA[((size_t)wr << 10) + slot], aU);
    }

    // ---- spin: h_t ready when all 32 wgs of group arrived t times ----
    if (t) {
      const unsigned target = (unsigned)t * 32u;
      unsigned c;
      while (1) {
        asm volatile("global_load_dword %0, %1, off sc0 sc1\n\ts_waitcnt vmcnt(0)"
                     : "=v"(c) : "v"(myc) : "memory");
        if (c >= target) break;
        __builtin_amdgcn_s_sleep(2);
      }
    }
    asm volatile("s_waitcnt vmcnt(0)" ::: "memory");
    __builtin_amdgcn_sched_barrier(0);

    // ---- phase H: aW/aL = h_hi/h_lo @ WB^T, depth-2 chunk pipeline ----
    s16x8 bufH[3][4], bufL[3][4];
    f32x4 aW = {0.f, 0.f, 0.f, 0.f}, aL = {0.f, 0.f, 0.f, 0.f};
    ISSUE_CHUNK(0, 0)
    ISSUE_CHUNK(1, 1)
#pragma unroll
    for (int c = 0; c < 8; ++c) {
      if (c < 6) {
        const int j = c + 2, sb = (c + 2) % 3;
        switch (sb) {  // constant under full unroll
          case 0: ISSUE_CHUNK(j, 0) break;
          case 1: ISSUE_CHUNK(j, 1) break;
          default: ISSUE_CHUNK(j, 2) break;
        }
        asm volatile("s_waitcnt vmcnt(16)" ::: "memory");
      } else if (c == 6) {
        asm volatile("s_waitcnt vmcnt(8)" ::: "memory");
      } else {
        asm volatile("s_waitcnt vmcnt(0)" ::: "memory");
      }
      __builtin_amdgcn_sched_barrier(0);
#pragma unroll
      for (int q = 0; q < 4; ++q) {
        const int kc = c * 4 + q;
        const int slot = (((kc * 4 + lgrp) ^ (wr & 7)) << 3);
        const s16x8 wb = *(const s16x8*)&sWB[((size_t)wr << 10) + slot];
        aW = mfma16(bufH[c % 3][q], wb, aW);
        aL = mfma16(bufL[c % 3][q], wb, aL);
      }
    }

    // ---- combine + LDS bounce -> coalesced 16B sc1 store per lane ----
#pragma unroll
    for (int r = 0; r < 4; ++r) {
      float v = aW[r] + aL[r] + aU[r] + bj;
      v = (v >= 0.f) ? v : LRELU_SLOPE * v;
      sT[wid][lgrp * 4 + r][lrow] = v;
    }
    asm volatile("s_waitcnt lgkmcnt(0)" ::: "memory");
    __builtin_amdgcn_sched_barrier(0);
    {
      float f[8];
#pragma unroll
      for (int e = 0; e < 8; ++e) f[e] = sT[wid][sr][sh2 * 8 + e];
      s16x8 ov;
#pragma unroll
      for (int e = 0; e < 8; ++e) {
        const u16 hv = f2bf(f[e]);
        const u16 o = (lane < 32) ? hv : f2bf(f[e] - bf2f(hv));
        ov[e] = (short)o;
      }
      u16* dst = ((lane < 32) ? ohh : ohl)
               + (((size_t)(b0 + wm * 16 + sr)) << 10) + j0 + wn * 16 + sh2 * 8;
      asm volatile("global_store_dwordx4 %0, %1, off sc0 sc1"
                   :: "v"(dst), "v"(ov) : "memory");
    }
    asm volatile("s_waitcnt vmcnt(0)" ::: "memory");
    __syncthreads();                       // joins 4 waves (stores all drained)
    if (tid == 0)
      __hip_atomic_fetch_add(myc, 1u, __ATOMIC_RELAXED, __HIP_MEMORY_SCOPE_AGENT);
  }
}

// ---------------- output GEMM (tiny, f32 VALU) -------------------------------

__global__ __launch_bounds__(256)
void out_gemm(const u16* __restrict__ hh, const u16* __restrict__ hl,
              const float* __restrict__ Wo, const float* __restrict__ bo,
              float* __restrict__ out) {
  __shared__ float hrow[1024];
  const int b = blockIdx.x, tid = threadIdx.x;
  for (int k = tid; k < 1024; k += 256)
    hrow[k] = bf2f(hh[((size_t)b << 10) + k]) + bf2f(hl[((size_t)b << 10) + k]);
  __syncthreads();
  const float* wo = Wo + (size_t)tid * 1024;
  float s0 = 0.f, s1 = 0.f, s2 = 0.f, s3 = 0.f;
  for (int k = 0; k < 1024; k += 4) {
    s0 = fmaf(wo[k + 0], hrow[k + 0], s0);
    s1 = fmaf(wo[k + 1], hrow[k + 1], s1);
    s2 = fmaf(wo[k + 2], hrow[k + 2], s2);
    s3 = fmaf(wo[k + 3], hrow[k + 3], s3);
  }
  out[(size_t)b * 256 + tid] = s0 + s1 + s2 + s3 + bo[tid];
}

// ---------------- launch ------------------------------------------------------

extern "C" void kernel_launch(void* const* d_in, const int* in_sizes, int n_in,
                              void* d_out, int out_size, void* d_ws, size_t ws_size,
                              hipStream_t stream) {
  const float* x  = (const float*)d_in[0];
  const float* Wi = (const float*)d_in[1];
  const float* bi = (const float*)d_in[2];
  const float* Wh = (const float*)d_in[3];
  const float* bh = (const float*)d_in[4];
  const float* Wo = (const float*)d_in[5];
  const float* bo = (const float*)d_in[6];

  char* w = (char*)d_ws;
  size_t off = 0;
  auto alloc = [&](size_t bytes) -> void* {
    void* p = w + off;
    off = (off + bytes + 255) & ~(size_t)255;
    return p;
  };
  u16* xh  = (u16*)alloc(33554432ull);    // x hi          [65536,256]
  u16* ph  = (u16*)alloc(134217728ull);   // xproj hi      [512][128][1024]
  u16* Wih = (u16*)alloc(524288ull);
  u16* Wil = (u16*)alloc(524288ull);
  u16* WAh = (u16*)alloc(2097152ull);     // Wh[:, :1024] hi
  u16* WBh = (u16*)alloc(2097152ull);     // Wh[:, 1024:] hi
  u16* h0h = (u16*)alloc(262144ull);
  u16* h0l = (u16*)alloc(262144ull);
  u16* h1h = (u16*)alloc(262144ull);
  u16* h1l = (u16*)alloc(262144ull);
  unsigned* cnt = (unsigned*)alloc(4096ull);
  const size_t needed = off;              // ~174 MB

  if (ws_size < needed) {                 // diagnostic fallback
    zero_out_k<<<(out_size + 255) / 256, 256, 0, stream>>>((float*)d_out, out_size);
    return;
  }

  hipMemsetAsync(cnt, 0, 4096, stream);
  hipMemsetAsync(h0h, 0, 262144, stream); // h_0 = 0
  hipMemsetAsync(h0l, 0, 262144, stream);

  splitHi  <<<16384, 256, 0, stream>>>(x, xh, 4194304);
  splitHiLo<<<256,   256, 0, stream>>>(Wi, Wih, Wil, 65536);
  split_wh <<<2048,  256, 0, stream>>>(Wh, WAh, WBh);

  gemm_xproj<<<dim3(512, 8), 256, 0, stream>>>(xh, Wih, Wil, bi, ph);

  recur<<<128, 256, 0, stream>>>(WAh, WBh, ph, bh, h0h, h0l, h1h, h1l, cnt);
  out_gemm<<<128, 256, 0, stream>>>(h0h, h0l, Wo, bo, (float*)d_out);
}

// Round 4
// 2373.667 us; speedup vs baseline: 9.1782x; 2.6443x over previous
//
#include <hip/hip_runtime.h>
#include <hip/hip_bf16.h>
#include <stdint.h>

// RNN_75531294867647 on MI355X (gfx950)
// B=128 S=512 I=256 H=1024 O=256, fp32 in/out, LeakyReLU slope 0.01.
//
//   split:  x -> bf16 hi; Wi -> hi/lo; Wh -> WA hi (cols 0:1024), WB hi (cols 1024:2048)
//   gemm1:  xproj = LReLU(x @ Wi^T + bi) -> bf16 hi, layout [S][B][H]  (128MB)
//   recur:  h <- LReLU(xproj_t @ WA^T + bh + (h_hi + h_lo) @ WB^T), 512 steps.
//           128 persistent wgs: 8 batch-groups (16 rows) x 16 j-wgs (64 cols).
//           4 waves = K-quarters; WB slice in LDS (128KB, XOR-swizzled); WA from
//           L2; xproj register-prefetched one step ahead; h exchange via
//           L3-direct (sc0 sc1); per-group 16-arrival relaxed atomic barrier.
//   out:    out = h @ Wo^T + bo (f32 VALU, tiny)

#define LRELU_SLOPE 0.01f

typedef unsigned short u16;
typedef __bf16 bf16x8 __attribute__((ext_vector_type(8)));
typedef short  s16x8  __attribute__((ext_vector_type(8)));
typedef float  f32x4  __attribute__((ext_vector_type(4)));
typedef u16    u16x4  __attribute__((ext_vector_type(4)));

__device__ __forceinline__ u16 f2bf(float f) {
  uint32_t u = __builtin_bit_cast(uint32_t, f);
  return (u16)((u + 0x7FFFu + ((u >> 16) & 1u)) >> 16);   // RNE
}
__device__ __forceinline__ float bf2f(u16 h) {
  uint32_t u = ((uint32_t)h) << 16;
  return __builtin_bit_cast(float, u);
}
__device__ __forceinline__ f32x4 mfma16(s16x8 a, s16x8 b, f32x4 c) {
  return __builtin_amdgcn_mfma_f32_16x16x32_bf16(
      __builtin_bit_cast(bf16x8, a), __builtin_bit_cast(bf16x8, b), c, 0, 0, 0);
}
__device__ __forceinline__ void gload_lds16(const void* g, void* l) {
  __builtin_amdgcn_global_load_lds(
      (const __attribute__((address_space(1))) void*)g,
      (__attribute__((address_space(3))) void*)l, 16, 0, 0);
}

// ---------------- fallback / split kernels -----------------------------------

__global__ void zero_out_k(float* __restrict__ out, int n) {
  int i = blockIdx.x * 256 + threadIdx.x;
  if (i < n) out[i] = 0.f;
}

__global__ void splitHi(const float* __restrict__ src, u16* __restrict__ hi, long n4) {
  long i = (long)blockIdx.x * 256 + threadIdx.x;
  if (i >= n4) return;
  float4 v = ((const float4*)src)[i];
  float a[4] = {v.x, v.y, v.z, v.w};
  u16x4 hv;
#pragma unroll
  for (int j = 0; j < 4; ++j) hv[j] = f2bf(a[j]);
  ((u16x4*)hi)[i] = hv;
}

__global__ void splitHiLo(const float* __restrict__ src, u16* __restrict__ hi,
                          u16* __restrict__ lo, long n4) {
  long i = (long)blockIdx.x * 256 + threadIdx.x;
  if (i >= n4) return;
  float4 v = ((const float4*)src)[i];
  float a[4] = {v.x, v.y, v.z, v.w};
  u16x4 hv, lv;
#pragma unroll
  for (int j = 0; j < 4; ++j) {
    u16 h = f2bf(a[j]);
    hv[j] = h;
    lv[j] = f2bf(a[j] - bf2f(h));
  }
  ((u16x4*)hi)[i] = hv;
  ((u16x4*)lo)[i] = lv;
}

// Wh [1024][2048] -> WAh = hi(cols 0:1024), WBh = hi(cols 1024:2048)
__global__ void split_wh(const float* __restrict__ Wh,
                         u16* __restrict__ WAh, u16* __restrict__ WBh) {
  long i4 = ((long)blockIdx.x * 256 + threadIdx.x) * 4;   // 1024*2048 elems
  int j = (int)(i4 >> 11), k2 = (int)(i4 & 2047);
  float4 v = *(const float4*)&Wh[i4];
  float a[4] = {v.x, v.y, v.z, v.w};
  u16x4 hv;
#pragma unroll
  for (int q = 0; q < 4; ++q) hv[q] = f2bf(a[q]);
  if (k2 < 1024) *(u16x4*)&WAh[(long)j * 1024 + k2]          = hv;
  else           *(u16x4*)&WBh[(long)j * 1024 + (k2 - 1024)] = hv;
}

// ---------------- gemm1: xproj = LReLU(x@Wi^T + bi) --------------------------

__global__ __launch_bounds__(256, 2)
void gemm_xproj(const u16* __restrict__ A, const u16* __restrict__ B0,
                const u16* __restrict__ B1, const float* __restrict__ bias,
                u16* __restrict__ outP) {
  __shared__ u16 sA[128 * 64], sB0[128 * 64], sB1[128 * 64];
  const int tid = threadIdx.x, wid = tid >> 6, lane = tid & 63;
  const int lrow = lane & 15, lgrp = lane >> 4;
  const int wm = wid >> 1, wn = wid & 1;
  const size_t m0 = (size_t)blockIdx.x * 128;
  const int n0 = blockIdx.y * 128;
  const int srow = tid >> 3, scol = (tid & 7) << 3;
  f32x4 acc[4][4] = {};

  for (int kt = 0; kt < 4; ++kt) {
    const int kph = kt << 6;
    __syncthreads();
#pragma unroll
    for (int sh = 0; sh < 4; ++sh) {
      const int r = sh * 32 + srow;
      gload_lds16(A  + (m0 + r) * 256 + kph + scol,          &sA [sh * 2048 + wid * 512]);
      gload_lds16(B0 + (size_t)(n0 + r) * 256 + kph + scol,  &sB0[sh * 2048 + wid * 512]);
      gload_lds16(B1 + (size_t)(n0 + r) * 256 + kph + scol,  &sB1[sh * 2048 + wid * 512]);
    }
    __syncthreads();
#pragma unroll
    for (int kk = 0; kk < 2; ++kk) {
      s16x8 bf0[4], bf1[4];
#pragma unroll
      for (int ni = 0; ni < 4; ++ni) {
        bf0[ni] = *(const s16x8*)&sB0[(wn * 64 + ni * 16 + lrow) * 64 + kk * 32 + lgrp * 8];
        bf1[ni] = *(const s16x8*)&sB1[(wn * 64 + ni * 16 + lrow) * 64 + kk * 32 + lgrp * 8];
      }
#pragma unroll
      for (int mi = 0; mi < 4; ++mi) {
        const s16x8 af = *(const s16x8*)&sA[(wm * 64 + mi * 16 + lrow) * 64 + kk * 32 + lgrp * 8];
#pragma unroll
        for (int ni = 0; ni < 4; ++ni) {
          acc[mi][ni] = mfma16(af, bf0[ni], acc[mi][ni]);
          acc[mi][ni] = mfma16(af, bf1[ni], acc[mi][ni]);
        }
      }
    }
  }
#pragma unroll
  for (int mi = 0; mi < 4; ++mi)
#pragma unroll
    for (int ni = 0; ni < 4; ++ni) {
      const int col = n0 + wn * 64 + ni * 16 + lrow;
      const float bv = bias[col];
#pragma unroll
      for (int r = 0; r < 4; ++r) {
        const size_t row = m0 + wm * 64 + mi * 16 + lgrp * 4 + r;
        float v = acc[mi][ni][r] + bv;
        v = (v >= 0.f) ? v : LRELU_SLOPE * v;
        const size_t b = row >> 9, s = row & 511;
        outP[(s * 128 + b) * 1024 + col] = f2bf(v);
      }
    }
}

// ---------------- recurrence -------------------------------------------------
// grid 128, 256 thr. wg: g = wg&7 (batch rows b0=16g..+16), jw = wg>>3
// (cols j0=64jw..+64). Waves = K-quarters kh=wid. LDS: sWB 64 rows (swizzled),
// sT[4][16][64] f32 partial-reduction buffer.
// Per step: aU = xproj_t@WA^T (xbuf regs prefetched, WA from L2, pre-spin);
// refill xbuf(t+1); spin cnt[g] >= 16*t; phase H: 16 sc0sc1 h-loads, counted
// vmcnt; partials -> sT; reduce + bias + LReLU + hi/lo split; 2B sc0sc1 stores;
// drain; syncthreads; tid0 relaxed arrival add.

__global__ __launch_bounds__(256, 1)
void recur(const u16* __restrict__ WAh, const u16* __restrict__ WBh,
           const u16* __restrict__ xproj, const float* __restrict__ bh,
           u16* __restrict__ h0h, u16* __restrict__ h0l,
           u16* __restrict__ h1h, u16* __restrict__ h1l,
           unsigned* __restrict__ cnt) {
  __shared__ u16 sWB[64 * 1024];          // 128 KB
  __shared__ float sT[4][16][64];         // 16 KB
  const int tid = threadIdx.x, wid = tid >> 6, lane = tid & 63;
  const int lrow = lane & 15, lgrp = lane >> 4;
  const int kh = wid;                     // K-quarter
  const int wg = blockIdx.x, g = wg & 7, jw = wg >> 3;
  const int b0 = g * 16, j0 = jw * 64;

  // WB slice rows j0..j0+64, 16B-granule XOR swizzle (slot = s ^ (r&7))
  for (int i = tid; i < 64 * 128; i += 256) {
    const int r = i >> 7, s = i & 127, sg = s ^ (r & 7);
    *(s16x8*)&sWB[(size_t)i * 8] = *(const s16x8*)&WBh[(((size_t)(j0 + r)) << 10) + sg * 8];
  }
  __syncthreads();

  const float bj = bh[j0 + lane];         // this thread's output col = lane
  unsigned* myc = &cnt[g * 256];          // group counters 1KB apart
  const size_t rowoff = (((size_t)(b0 + lrow)) << 10) + kh * 256 + lgrp * 8;
  const u16* waL = WAh + (((size_t)(j0 + lrow)) << 10) + kh * 256 + lgrp * 8;

  // prologue: xbuf <- xproj_0
  s16x8 xbuf[8];
#pragma unroll
  for (int kc = 0; kc < 8; ++kc)
    asm volatile("global_load_dwordx4 %0, %1, off"
                 : "=v"(xbuf[kc]) : "v"(xproj + rowoff + kc * 32));
  asm volatile("s_waitcnt vmcnt(0)" ::: "memory");

  for (int t = 0; t < 512; ++t) {
    const u16* hh = (t & 1) ? h1h : h0h;
    const u16* hl = (t & 1) ? h1l : h0l;
    u16* ohh = (t & 1) ? h0h : h1h;
    u16* ohl = (t & 1) ? h0l : h1l;
    const u16* hhp = hh + rowoff;
    const u16* hlp = hl + rowoff;

    // ---- phase U: acc = xproj_t @ WA^T (independent of h_t, pre-spin) ----
    f32x4 acc[4] = {{0.f,0.f,0.f,0.f},{0.f,0.f,0.f,0.f},{0.f,0.f,0.f,0.f},{0.f,0.f,0.f,0.f}};
#pragma unroll
    for (int n = 0; n < 4; ++n) {
#pragma unroll
      for (int kc = 0; kc < 8; ++kc) {
        const s16x8 wa = *(const s16x8*)(waL + ((size_t)n << 14) + kc * 32);
        acc[n] = mfma16(xbuf[kc], wa, acc[n]);
      }
    }

    // ---- refill xbuf for t+1 (cached; completes during spin/phase H) ----
    {
      const u16* xnext = xproj + (((size_t)(t + 1)) << 17) + rowoff;
#pragma unroll
      for (int kc = 0; kc < 8; ++kc)
        asm volatile("global_load_dwordx4 %0, %1, off"
                     : "=v"(xbuf[kc]) : "v"(xnext + kc * 32));
    }

    // ---- spin: h_t ready when all 16 wgs of group arrived t times ----
    if (t) {
      const unsigned target = (unsigned)t * 16u;
      unsigned c;
      while (1) {
        asm volatile("global_load_dword %0, %1, off sc0 sc1\n\ts_waitcnt vmcnt(0)"
                     : "=v"(c) : "v"(myc) : "memory");
        if (c >= target) break;
        __builtin_amdgcn_s_sleep(1);
      }
    }
    __builtin_amdgcn_sched_barrier(0);

    // ---- phase H: acc += (h_hi + h_lo) @ WB^T, all 16 loads in flight ----
    s16x8 hb[8], lb[8];
#pragma unroll
    for (int kc = 0; kc < 8; ++kc) {
      asm volatile("global_load_dwordx4 %0, %1, off sc0 sc1"
                   : "=v"(hb[kc]) : "v"(hhp + kc * 32));
      asm volatile("global_load_dwordx4 %0, %1, off sc0 sc1"
                   : "=v"(lb[kc]) : "v"(hlp + kc * 32));
    }
#pragma unroll
    for (int kc = 0; kc < 8; ++kc) {
      switch (kc) {   // literal vmcnt: pairs retire oldest-first
        case 0: asm volatile("s_waitcnt vmcnt(14)" ::: "memory"); break;
        case 1: asm volatile("s_waitcnt vmcnt(12)" ::: "memory"); break;
        case 2: asm volatile("s_waitcnt vmcnt(10)" ::: "memory"); break;
        case 3: asm volatile("s_waitcnt vmcnt(8)"  ::: "memory"); break;
        case 4: asm volatile("s_waitcnt vmcnt(6)"  ::: "memory"); break;
        case 5: asm volatile("s_waitcnt vmcnt(4)"  ::: "memory"); break;
        case 6: asm volatile("s_waitcnt vmcnt(2)"  ::: "memory"); break;
        default: asm volatile("s_waitcnt vmcnt(0)" ::: "memory"); break;
      }
      __builtin_amdgcn_sched_barrier(0);
      const int ka = kh * 32 + kc * 4 + lgrp;
#pragma unroll
      for (int n = 0; n < 4; ++n) {
        const int wr = n * 16 + lrow;
        const s16x8 wb = *(const s16x8*)&sWB[((size_t)wr << 10) + ((ka ^ (wr & 7)) << 3)];
        acc[n] = mfma16(hb[kc], wb, acc[n]);
        acc[n] = mfma16(lb[kc], wb, acc[n]);
      }
    }

    // ---- partials -> sT, reduce across K-quarters, activate, store ----
#pragma unroll
    for (int n = 0; n < 4; ++n)
#pragma unroll
      for (int r = 0; r < 4; ++r)
        sT[kh][lgrp * 4 + r][n * 16 + lrow] = acc[n][r];
    __syncthreads();
#pragma unroll
    for (int k2 = 0; k2 < 4; ++k2) {
      const int r = wid + k2 * 4;
      float v = sT[0][r][lane] + sT[1][r][lane] + sT[2][r][lane] + sT[3][r][lane] + bj;
      v = (v >= 0.f) ? v : LRELU_SLOPE * v;
      const u16 hB = f2bf(v);
      const u16 lB = f2bf(v - bf2f(hB));
      u16* dh = ohh + (((size_t)(b0 + r)) << 10) + j0 + lane;
      u16* dl = ohl + (((size_t)(b0 + r)) << 10) + j0 + lane;
      asm volatile("global_store_short %0, %1, off sc0 sc1"
                   :: "v"(dh), "v"((unsigned)hB) : "memory");
      asm volatile("global_store_short %0, %1, off sc0 sc1"
                   :: "v"(dl), "v"((unsigned)lB) : "memory");
    }
    asm volatile("s_waitcnt vmcnt(0)" ::: "memory");   // h stores + refill drained
    __syncthreads();
    if (tid == 0)
      __hip_atomic_fetch_add(myc, 1u, __ATOMIC_RELAXED, __HIP_MEMORY_SCOPE_AGENT);
  }
}

// ---------------- output GEMM (tiny, f32 VALU) -------------------------------

__global__ __launch_bounds__(256)
void out_gemm(const u16* __restrict__ hh, const u16* __restrict__ hl,
              const float* __restrict__ Wo, const float* __restrict__ bo,
              float* __restrict__ out) {
  __shared__ float hrow[1024];
  const int b = blockIdx.x, tid = threadIdx.x;
  for (int k = tid; k < 1024; k += 256)
    hrow[k] = bf2f(hh[((size_t)b << 10) + k]) + bf2f(hl[((size_t)b << 10) + k]);
  __syncthreads();
  const float* wo = Wo + (size_t)tid * 1024;
  float s0 = 0.f, s1 = 0.f, s2 = 0.f, s3 = 0.f;
  for (int k = 0; k < 1024; k += 4) {
    s0 = fmaf(wo[k + 0], hrow[k + 0], s0);
    s1 = fmaf(wo[k + 1], hrow[k + 1], s1);
    s2 = fmaf(wo[k + 2], hrow[k + 2], s2);
    s3 = fmaf(wo[k + 3], hrow[k + 3], s3);
  }
  out[(size_t)b * 256 + tid] = s0 + s1 + s2 + s3 + bo[tid];
}

// ---------------- launch ------------------------------------------------------

extern "C" void kernel_launch(void* const* d_in, const int* in_sizes, int n_in,
                              void* d_out, int out_size, void* d_ws, size_t ws_size,
                              hipStream_t stream) {
  const float* x  = (const float*)d_in[0];
  const float* Wi = (const float*)d_in[1];
  const float* bi = (const float*)d_in[2];
  const float* Wh = (const float*)d_in[3];
  const float* bh = (const float*)d_in[4];
  const float* Wo = (const float*)d_in[5];
  const float* bo = (const float*)d_in[6];

  char* w = (char*)d_ws;
  size_t off = 0;
  auto alloc = [&](size_t bytes) -> void* {
    void* p = w + off;
    off = (off + bytes + 255) & ~(size_t)255;
    return p;
  };
  u16* xh  = (u16*)alloc(33554432ull);    // x hi          [65536,256]
  u16* ph  = (u16*)alloc(134217728ull);   // xproj hi      [512][128][1024]
  u16* Wih = (u16*)alloc(524288ull);
  u16* Wil = (u16*)alloc(524288ull);
  u16* WAh = (u16*)alloc(2097152ull);     // Wh[:, :1024] hi
  u16* WBh = (u16*)alloc(2097152ull);     // Wh[:, 1024:] hi
  u16* h0h = (u16*)alloc(262144ull);
  u16* h0l = (u16*)alloc(262144ull);
  u16* h1h = (u16*)alloc(262144ull);
  u16* h1l = (u16*)alloc(262144ull);
  unsigned* cnt = (unsigned*)alloc(16384ull);
  const size_t needed = off;              // ~174 MB

  if (ws_size < needed) {                 // diagnostic fallback
    zero_out_k<<<(out_size + 255) / 256, 256, 0, stream>>>((float*)d_out, out_size);
    return;
  }

  hipMemsetAsync(cnt, 0, 16384, stream);
  hipMemsetAsync(h0h, 0, 262144, stream); // h_0 = 0
  hipMemsetAsync(h0l, 0, 262144, stream);

  splitHi  <<<16384, 256, 0, stream>>>(x, xh, 4194304);
  splitHiLo<<<256,   256, 0, stream>>>(Wi, Wih, Wil, 65536);
  split_wh <<<2048,  256, 0, stream>>>(Wh, WAh, WBh);

  gemm_xproj<<<dim3(512, 8), 256, 0, stream>>>(xh, Wih, Wil, bi, ph);

  recur<<<128, 256, 0, stream>>>(WAh, WBh, ph, bh, h0h, h0l, h1h, h1l, cnt);
  out_gemm<<<128, 256, 0, stream>>>(h0h, h0l, Wo, bo, (float*)d_out);
}